// Round 1
// baseline (753.044 us; speedup 1.0000x reference)
//
#include <hip/hip_runtime.h>
#include <stdint.h>

// Problem constants
#define BATCH 2
#define SEQ   2048
#define NH    16
#define DH    128
#define DM    2048      // NH*DH
#define NQKV  6144      // 3*DM
#define MROWS 4096      // BATCH*SEQ

typedef __bf16 bf16x8 __attribute__((ext_vector_type(8)));
typedef float  f32x4  __attribute__((ext_vector_type(4)));

__device__ __forceinline__ void gl_lds16(const void* g, void* l) {
  __builtin_amdgcn_global_load_lds(
      (const __attribute__((address_space(1))) void*)g,
      (__attribute__((address_space(3))) void*)l, 16, 0, 0);
}

// fp32 -> bf16 (RNE)
__device__ __forceinline__ unsigned short f2bf(float f) {
  uint32_t u = __builtin_bit_cast(uint32_t, f);
  return (unsigned short)((u + 0x7FFFu + ((u >> 16) & 1u)) >> 16);
}

// ---------------- prep kernels ----------------
__global__ void convert_x_kernel(const float* __restrict__ in,
                                 unsigned short* __restrict__ out) {
  int i = blockIdx.x * 256 + threadIdx.x;          // one float4 per thread
  float4 v = ((const float4*)in)[i];
  uint32_t lo = (uint32_t)f2bf(v.x) | ((uint32_t)f2bf(v.y) << 16);
  uint32_t hi = (uint32_t)f2bf(v.z) | ((uint32_t)f2bf(v.w) << 16);
  ((uint2*)out)[i] = make_uint2(lo, hi);
}

// in fp32 [K,N] row-major -> out bf16 [N,K] row-major
__global__ void transpose_w_kernel(const float* __restrict__ in,
                                   unsigned short* __restrict__ out,
                                   int K, int N) {
  __shared__ float tile[32][33];
  const int tx = threadIdx.x, ty = threadIdx.y;    // 32 x 8
  const int n0 = blockIdx.x * 32, k0 = blockIdx.y * 32;
  #pragma unroll
  for (int i = 0; i < 32; i += 8)
    tile[ty + i][tx] = in[(size_t)(k0 + ty + i) * N + n0 + tx];
  __syncthreads();
  #pragma unroll
  for (int i = 0; i < 32; i += 8)
    out[(size_t)(n0 + ty + i) * K + k0 + tx] = f2bf(tile[tx][ty + i]);
}

// ---------------- QKV GEMM (m97 gemm_bt structure) ----------------
// A [4096,2048] bf16, Bt [6144,2048] bf16. C scattered into Q/K [bh,s,d], Vt [bh,d,s].
__global__ void qkv_gemm_kernel(const unsigned short* __restrict__ A,
                                const unsigned short* __restrict__ Bt,
                                const float* __restrict__ bias,
                                unsigned short* __restrict__ Qb,
                                unsigned short* __restrict__ Kb,
                                unsigned short* __restrict__ Vtb) {
  __shared__ alignas(16) unsigned short As[128 * 32];
  __shared__ alignas(16) unsigned short Bs[128 * 32];
  const int tid = threadIdx.x;
  const int lane = tid & 63, wave = tid >> 6;
  const int wm = wave >> 1, wn = wave & 1;
  const int quad = lane >> 4, l15 = lane & 15;
  const int bm = blockIdx.x, bn = blockIdx.y;
  const int K = DM;

  f32x4 acc[4][4];
  #pragma unroll
  for (int i = 0; i < 4; ++i)
    #pragma unroll
    for (int j = 0; j < 4; ++j) acc[i][j] = (f32x4){0.f, 0.f, 0.f, 0.f};

  const unsigned short* Ag = A + (size_t)(bm * 128 + (tid >> 2)) * K + (tid & 3) * 8;
  const unsigned short* Bg = Bt + (size_t)(bn * 128 + (tid >> 2)) * K + (tid & 3) * 8;

  for (int kt = 0; kt < K / 32; ++kt) {
    gl_lds16(Ag + kt * 32,                As + tid * 8);
    gl_lds16(Ag + (size_t)64 * K + kt * 32, As + 2048 + tid * 8);
    gl_lds16(Bg + kt * 32,                Bs + tid * 8);
    gl_lds16(Bg + (size_t)64 * K + kt * 32, Bs + 2048 + tid * 8);
    __syncthreads();
    bf16x8 af[4], bfr[4];
    #pragma unroll
    for (int mi = 0; mi < 4; ++mi)
      af[mi] = *(const bf16x8*)(As + (wm * 64 + mi * 16 + l15) * 32 + quad * 8);
    #pragma unroll
    for (int ni = 0; ni < 4; ++ni)
      bfr[ni] = *(const bf16x8*)(Bs + (wn * 64 + ni * 16 + l15) * 32 + quad * 8);
    #pragma unroll
    for (int mi = 0; mi < 4; ++mi)
      #pragma unroll
      for (int ni = 0; ni < 4; ++ni)
        acc[mi][ni] = __builtin_amdgcn_mfma_f32_16x16x32_bf16(af[mi], bfr[ni], acc[mi][ni], 0, 0, 0);
    __syncthreads();
  }

  // epilogue: C/D layout col=lane&15, row=quad*4+reg [verified m89/m91]
  #pragma unroll
  for (int mi = 0; mi < 4; ++mi) {
    #pragma unroll
    for (int ni = 0; ni < 4; ++ni) {
      const int grow0 = bm * 128 + wm * 64 + mi * 16 + quad * 4;
      const int gcol  = bn * 128 + wn * 64 + ni * 16 + l15;
      const float bv = bias[gcol];
      const int which = gcol >> 11;          // 0=Q 1=K 2=V
      const int rem = gcol & 2047;
      const int h = rem >> 7, d = rem & 127;
      #pragma unroll
      for (int r = 0; r < 4; ++r) {
        const int grow = grow0 + r;
        const int b = grow >> 11, s = grow & 2047;
        const int bh = b * NH + h;
        const unsigned short val = f2bf(acc[mi][ni][r] + bv);
        if (which == 0)      Qb[((size_t)bh * SEQ + s) * DH + d] = val;
        else if (which == 1) Kb[((size_t)bh * SEQ + s) * DH + d] = val;
        else                 Vtb[((size_t)bh * DH + d) * SEQ + s] = val;   // V transposed
      }
    }
  }
}

// ---------------- flash attention ----------------
// grid (16 qtiles, 32 bh), 256 threads. Per block: 128 q rows; per wave: 32 q rows.
__global__ void attn_kernel(const unsigned short* __restrict__ Qb,   // [32,2048,128]
                            const unsigned short* __restrict__ Kb,   // [32,2048,128]
                            const unsigned short* __restrict__ Vtb,  // [32,128,2048]
                            unsigned short* __restrict__ Ob) {       // [4096,2048] = [B,S,H*D]
  __shared__ alignas(16) unsigned short Ks[64 * 128];   // [kv][d]
  __shared__ alignas(16) unsigned short Vs[128 * 64];   // [d][kv]  (from Vt)
  __shared__ alignas(16) unsigned short Ps[4][32 * 64]; // per-wave P tile [q][kv]
  const int tid = threadIdx.x, lane = tid & 63, wave = tid >> 6;
  const int quad = lane >> 4, l15 = lane & 15;
  const int bh = blockIdx.y;
  const int qb = (int)(gridDim.x - 1) - (int)blockIdx.x;  // longest blocks first
  const int b = bh >> 4, h = bh & 15;
  const int q0 = qb * 128 + wave * 32;

  // Q fragments in registers: A-layout m=lane&15, k=quad*8+j [m120]
  bf16x8 qf[2][4];
  #pragma unroll
  for (int mi = 0; mi < 2; ++mi)
    #pragma unroll
    for (int ds = 0; ds < 4; ++ds)
      qf[mi][ds] = *(const bf16x8*)(Qb + ((size_t)bh * SEQ + q0 + mi * 16 + l15) * DH + ds * 32 + quad * 8);

  f32x4 o[2][8];
  #pragma unroll
  for (int mi = 0; mi < 2; ++mi)
    #pragma unroll
    for (int di = 0; di < 8; ++di) o[mi][di] = (f32x4){0.f, 0.f, 0.f, 0.f};
  float m_i[2][4], l_i[2][4];
  #pragma unroll
  for (int mi = 0; mi < 2; ++mi)
    #pragma unroll
    for (int r = 0; r < 4; ++r) { m_i[mi][r] = -INFINITY; l_i[mi][r] = 0.f; }

  const float c = 0.08838834764831845f * 1.4426950408889634f; // 1/sqrt(128) * log2(e)

  const int nkt = (qb + 1) * 2;   // 64-wide kv tiles
  for (int kt = 0; kt < nkt; ++kt) {
    #pragma unroll
    for (int r = 0; r < 4; ++r) {   // stage K tile (16KB) + Vt tile (16KB)
      const int idx = r * 256 + tid;
      gl_lds16(Kb + ((size_t)bh * SEQ + kt * 64 + (idx >> 4)) * DH + (idx & 15) * 8, Ks + idx * 8);
      gl_lds16(Vtb + ((size_t)bh * DH + (idx >> 3)) * SEQ + kt * 64 + (idx & 7) * 8, Vs + idx * 8);
    }
    __syncthreads();

    // S = Q K^T (gemm_bt: B-operand = K rows, k-contiguous in d)
    f32x4 s_acc[2][4];
    #pragma unroll
    for (int mi = 0; mi < 2; ++mi)
      #pragma unroll
      for (int ni = 0; ni < 4; ++ni) s_acc[mi][ni] = (f32x4){0.f, 0.f, 0.f, 0.f};
    #pragma unroll
    for (int ds = 0; ds < 4; ++ds) {
      bf16x8 kf[4];
      #pragma unroll
      for (int ni = 0; ni < 4; ++ni)
        kf[ni] = *(const bf16x8*)(Ks + (ni * 16 + l15) * 128 + ds * 32 + quad * 8);
      #pragma unroll
      for (int mi = 0; mi < 2; ++mi)
        #pragma unroll
        for (int ni = 0; ni < 4; ++ni)
          s_acc[mi][ni] = __builtin_amdgcn_mfma_f32_16x16x32_bf16(qf[mi][ds], kf[ni], s_acc[mi][ni], 0, 0, 0);
    }

    // scale into 2^x domain + causal mask
    #pragma unroll
    for (int mi = 0; mi < 2; ++mi)
      #pragma unroll
      for (int ni = 0; ni < 4; ++ni) {
        const int kcol = kt * 64 + ni * 16 + l15;
        #pragma unroll
        for (int r = 0; r < 4; ++r) {
          float v = s_acc[mi][ni][r] * c;
          const int qrow = q0 + mi * 16 + quad * 4 + r;
          if (kcol > qrow) v = -INFINITY;
          s_acc[mi][ni][r] = v;
        }
      }

    // online softmax; rows live in one 16-lane group (C-layout) -> shfl_xor <=8
    #pragma unroll
    for (int mi = 0; mi < 2; ++mi) {
      float rmax[4], alpha[4], rsum[4];
      #pragma unroll
      for (int r = 0; r < 4; ++r)
        rmax[r] = fmaxf(fmaxf(s_acc[mi][0][r], s_acc[mi][1][r]),
                        fmaxf(s_acc[mi][2][r], s_acc[mi][3][r]));
      #pragma unroll
      for (int off = 8; off >= 1; off >>= 1)
        #pragma unroll
        for (int r = 0; r < 4; ++r)
          rmax[r] = fmaxf(rmax[r], __shfl_xor(rmax[r], off, 64));
      #pragma unroll
      for (int r = 0; r < 4; ++r) {
        const float mnew = fmaxf(m_i[mi][r], rmax[r]);
        alpha[r] = exp2f(m_i[mi][r] - mnew);   // exp2(-inf)=0 on first tile
        m_i[mi][r] = mnew;
        rsum[r] = 0.f;
      }
      #pragma unroll
      for (int ni = 0; ni < 4; ++ni)
        #pragma unroll
        for (int r = 0; r < 4; ++r) {
          const float p = exp2f(s_acc[mi][ni][r] - m_i[mi][r]);
          s_acc[mi][ni][r] = p;
          rsum[r] += p;
        }
      #pragma unroll
      for (int off = 8; off >= 1; off >>= 1)
        #pragma unroll
        for (int r = 0; r < 4; ++r)
          rsum[r] += __shfl_xor(rsum[r], off, 64);
      #pragma unroll
      for (int r = 0; r < 4; ++r) l_i[mi][r] = l_i[mi][r] * alpha[r] + rsum[r];
      #pragma unroll
      for (int di = 0; di < 8; ++di)
        #pragma unroll
        for (int r = 0; r < 4; ++r) o[mi][di][r] *= alpha[r];
      // P: C-layout -> LDS -> A-layout (m120 round-trip)
      #pragma unroll
      for (int ni = 0; ni < 4; ++ni)
        #pragma unroll
        for (int r = 0; r < 4; ++r)
          Ps[wave][(mi * 16 + quad * 4 + r) * 64 + ni * 16 + l15] = f2bf(s_acc[mi][ni][r]);
    }

    // O += P V   (B-operand = Vt rows, k-contiguous)
    #pragma unroll
    for (int ks = 0; ks < 2; ++ks) {
      bf16x8 pf[2];
      #pragma unroll
      for (int mi = 0; mi < 2; ++mi)
        pf[mi] = *(const bf16x8*)(&Ps[wave][(mi * 16 + l15) * 64 + ks * 32 + quad * 8]);
      #pragma unroll
      for (int di = 0; di < 8; ++di) {
        const bf16x8 vf = *(const bf16x8*)(Vs + (di * 16 + l15) * 64 + ks * 32 + quad * 8);
        #pragma unroll
        for (int mi = 0; mi < 2; ++mi)
          o[mi][di] = __builtin_amdgcn_mfma_f32_16x16x32_bf16(pf[mi], vf, o[mi][di], 0, 0, 0);
      }
    }
    __syncthreads();
  }

  // normalize + write [B,S,H*D] bf16
  #pragma unroll
  for (int mi = 0; mi < 2; ++mi) {
    float inv[4];
    #pragma unroll
    for (int r = 0; r < 4; ++r) inv[r] = 1.0f / l_i[mi][r];
    #pragma unroll
    for (int di = 0; di < 8; ++di)
      #pragma unroll
      for (int r = 0; r < 4; ++r) {
        const int qrow = q0 + mi * 16 + quad * 4 + r;
        Ob[((size_t)(b * SEQ + qrow)) * DM + h * DH + di * 16 + l15] = f2bf(o[mi][di][r] * inv[r]);
      }
  }
}

// ---------------- out projection GEMM ----------------
__global__ void out_gemm_kernel(const unsigned short* __restrict__ A,   // [4096,2048] bf16
                                const unsigned short* __restrict__ Bt,  // [2048,2048] bf16 (W_out^T)
                                const float* __restrict__ bias,
                                float* __restrict__ out) {
  __shared__ alignas(16) unsigned short As[128 * 32];
  __shared__ alignas(16) unsigned short Bs[128 * 32];
  const int tid = threadIdx.x;
  const int lane = tid & 63, wave = tid >> 6;
  const int wm = wave >> 1, wn = wave & 1;
  const int quad = lane >> 4, l15 = lane & 15;
  const int bm = blockIdx.x, bn = blockIdx.y;
  const int K = DM;

  f32x4 acc[4][4];
  #pragma unroll
  for (int i = 0; i < 4; ++i)
    #pragma unroll
    for (int j = 0; j < 4; ++j) acc[i][j] = (f32x4){0.f, 0.f, 0.f, 0.f};

  const unsigned short* Ag = A + (size_t)(bm * 128 + (tid >> 2)) * K + (tid & 3) * 8;
  const unsigned short* Bg = Bt + (size_t)(bn * 128 + (tid >> 2)) * K + (tid & 3) * 8;

  for (int kt = 0; kt < K / 32; ++kt) {
    gl_lds16(Ag + kt * 32,                  As + tid * 8);
    gl_lds16(Ag + (size_t)64 * K + kt * 32, As + 2048 + tid * 8);
    gl_lds16(Bg + kt * 32,                  Bs + tid * 8);
    gl_lds16(Bg + (size_t)64 * K + kt * 32, Bs + 2048 + tid * 8);
    __syncthreads();
    bf16x8 af[4], bfr[4];
    #pragma unroll
    for (int mi = 0; mi < 4; ++mi)
      af[mi] = *(const bf16x8*)(As + (wm * 64 + mi * 16 + l15) * 32 + quad * 8);
    #pragma unroll
    for (int ni = 0; ni < 4; ++ni)
      bfr[ni] = *(const bf16x8*)(Bs + (wn * 64 + ni * 16 + l15) * 32 + quad * 8);
    #pragma unroll
    for (int mi = 0; mi < 4; ++mi)
      #pragma unroll
      for (int ni = 0; ni < 4; ++ni)
        acc[mi][ni] = __builtin_amdgcn_mfma_f32_16x16x32_bf16(af[mi], bfr[ni], acc[mi][ni], 0, 0, 0);
    __syncthreads();
  }

  #pragma unroll
  for (int mi = 0; mi < 4; ++mi) {
    #pragma unroll
    for (int ni = 0; ni < 4; ++ni) {
      const int grow0 = bm * 128 + wm * 64 + mi * 16 + quad * 4;
      const int gcol  = bn * 128 + wn * 64 + ni * 16 + l15;
      const float bv = bias[gcol];
      #pragma unroll
      for (int r = 0; r < 4; ++r)
        out[(size_t)(grow0 + r) * DM + gcol] = acc[mi][ni][r] + bv;
    }
  }
}

// ---------------- launch ----------------
extern "C" void kernel_launch(void* const* d_in, const int* in_sizes, int n_in,
                              void* d_out, int out_size, void* d_ws, size_t ws_size,
                              hipStream_t stream) {
  const float* x     = (const float*)d_in[0];   // [2,2048,2048]
  const float* W_qkv = (const float*)d_in[1];   // [2048,6144]
  const float* b_qkv = (const float*)d_in[2];   // [6144]
  const float* W_out = (const float*)d_in[3];   // [2048,2048]
  const float* b_out = (const float*)d_in[4];   // [2048]
  float* out = (float*)d_out;                   // [4096,2048]

  char* ws = (char*)d_ws;
  unsigned short* xb    = (unsigned short*)(ws);                 // 16 MB  [4096,2048]
  unsigned short* WqkvT = (unsigned short*)(ws + 16777216ull);   // 24 MB  [6144,2048]
  unsigned short* WoutT = (unsigned short*)(ws + 41943040ull);   //  8 MB  [2048,2048]
  unsigned short* Qb    = (unsigned short*)(ws + 50331648ull);   // 16 MB  [32,2048,128]
  unsigned short* Kb    = (unsigned short*)(ws + 67108864ull);   // 16 MB  [32,2048,128]
  unsigned short* Vtb   = (unsigned short*)(ws + 83886080ull);   // 16 MB  [32,128,2048]
  unsigned short* attnb = (unsigned short*)(ws + 100663296ull);  // 16 MB  [4096,2048]

  convert_x_kernel<<<dim3(8192), dim3(256), 0, stream>>>(x, xb);
  transpose_w_kernel<<<dim3(192, 64), dim3(32, 8), 0, stream>>>(W_qkv, WqkvT, DM, NQKV);
  transpose_w_kernel<<<dim3(64, 64), dim3(32, 8), 0, stream>>>(W_out, WoutT, DM, DM);
  qkv_gemm_kernel<<<dim3(32, 48), dim3(256), 0, stream>>>(xb, WqkvT, b_qkv, Qb, Kb, Vtb);
  attn_kernel<<<dim3(16, 32), dim3(256), 0, stream>>>(Qb, Kb, Vtb, attnb);
  out_gemm_kernel<<<dim3(32, 16), dim3(256), 0, stream>>>(attnb, WoutT, b_out, out);
}